// Round 6
// baseline (1021.814 us; speedup 1.0000x reference)
//
#include <hip/hip_runtime.h>
#include <hip/hip_bf16.h>
#include <stdint.h>

#define T_ 64
#define N_ 1024
#define L_ 128
#define H_ 512
#define C_ 64
#define S_ 771          // 1 + 1 + H + (L+1) + L
#define TN_ (T_*N_)

typedef unsigned short u16;
typedef unsigned int u32;
typedef float f32x4 __attribute__((ext_vector_type(4)));
typedef __bf16 bf16x8 __attribute__((ext_vector_type(8)));
typedef u16 u16x8 __attribute__((ext_vector_type(8)));

#define WAITVM(n) do { asm volatile("s_waitcnt vmcnt(" #n ")" ::: "memory"); \
                       __builtin_amdgcn_sched_barrier(0); } while (0)

__device__ __forceinline__ u16 f2bf(float f) {
  u32 u = __float_as_uint(f);
  u32 r = (u + 0x7FFFu + ((u >> 16) & 1u)) >> 16;
  return (u16)r;
}
__device__ __forceinline__ float bf2f(u16 u) {
  return __uint_as_float(((u32)u) << 16);
}
__device__ __forceinline__ void gload16(const void* g, void* l) {
  __builtin_amdgcn_global_load_lds((const __attribute__((address_space(1))) u32*)g,
                                   (__attribute__((address_space(3))) u32*)l, 16, 0, 0);
}
__device__ __forceinline__ float sigm(float x) { return 1.0f / (1.0f + __expf(-x)); }

// LLC-coherent (device-scope) accesses: sc0 sc1 = bypass/write-through L1+L2.
// Proven in round 4: these carry the h exchange with NO wbl2/inv maintenance.
__device__ __forceinline__ bf16x8 load_cc(const u16* p) {
  bf16x8 v;
  asm volatile("global_load_dwordx4 %0, %1, off sc0 sc1" : "=v"(v) : "v"(p) : "memory");
  return v;
}
__device__ __forceinline__ void store_cc_d2(u16* p, uint2 val) {
  asm volatile("global_store_dwordx2 %0, %1, off sc0 sc1" :: "v"(p), "v"(val) : "memory");
}
__device__ __forceinline__ float gi_get(uint2 u, int v) {
  u32 w = (v < 2) ? u.x : u.y;
  u16 h = (v & 1) ? (u16)(w >> 16) : (u16)(w & 0xffffu);
  return bf2f(h);
}

// ---------------- prep kernels ----------------
__global__ void cast_f32_bf16(const float* __restrict__ src, u16* __restrict__ dst, int n) {
  int i = blockIdx.x * 256 + threadIdx.x;
  if (i < n) dst[i] = f2bf(src[i]);
}

__global__ void qscan(const float* __restrict__ hxs, const int* __restrict__ actions,
                      int* __restrict__ qpre, int* __restrict__ qpost) {
  int n = blockIdx.x * 256 + threadIdx.x;
  if (n >= N_) return;
  bool nz = false;
  for (int s = 0; s < S_; ++s) nz |= (hxs[(size_t)n * S_ + s] != 0.0f);
  int q = 0;
  if (nz) {  // fallback: argmax of stored one-hot p0
    float best = -3.4e38f;
    for (int l = 0; l < L_; ++l) {
      float v = hxs[(size_t)n * S_ + 2 + H_ + (L_ + 1) + l];
      if (v > best) { best = v; q = l; }
    }
  }
  for (int t = 0; t < T_; ++t) {
    qpre[t * N_ + n] = q;
    int a = actions[t * N_ + n];
    if (a < L_) q = a;
    qpost[t * N_ + n] = q;
  }
}

// writes h_init (bf16) into Hsave slot 0
__global__ void hbf_init(const float* __restrict__ hxs, u16* __restrict__ hsave0) {
  int i = blockIdx.x * 256 + threadIdx.x;
  if (i >= N_ * H_) return;
  int n = i >> 9, j = i & 511;
  hsave0[i] = f2bf(hxs[(size_t)n * S_ + 2 + j]);
}

// A = [cond_t | emb[lines[n, qpre]]] as bf16 (TN x 576); one wave per row
__global__ void build_abuf(const float* __restrict__ cond, const float* __restrict__ emb,
                           const int* __restrict__ lines, const int* __restrict__ qpre,
                           u16* __restrict__ abuf) {
  int row = blockIdx.x * 4 + (threadIdx.x >> 6);
  int lane = threadIdx.x & 63;
  int n = row & (N_ - 1);
  int q = qpre[row];
  int line = lines[n * L_ + q];
  abuf[(size_t)row * 576 + lane] = f2bf(cond[(size_t)row * 64 + lane]);
  const float* er = emb + (size_t)line * H_;
  u16* ar = abuf + (size_t)row * 576 + 64;
  for (int j = lane; j < H_; j += 64) ar[j] = f2bf(er[j]);
}

// ---------------- phase-A GEMM (m97-style 128x128, BK=64, NT, bias[+relu], bf16 out) ----------------
#define BM 128
#define BN 128
#define BK 64
__global__ __launch_bounds__(256) void gemm_nt(
    const u16* __restrict__ A, int lda,
    const u16* __restrict__ B, int ldb,
    const float* __restrict__ bias,
    u16* __restrict__ C, int ldc,
    int K, int relu)
{
  __shared__ __align__(16) u16 lA[BM * BK];
  __shared__ __align__(16) u16 lB[BN * BK];
  int tid = threadIdx.x;
  int lane = tid & 63;
  int wave = tid >> 6;
  int wm = wave >> 1, wn = wave & 1;
  int m0 = blockIdx.y * BM;
  int n0 = blockIdx.x * BN;

  f32x4 acc[4][4];
  f32x4 zero = {0.f, 0.f, 0.f, 0.f};
#pragma unroll
  for (int i = 0; i < 4; ++i)
#pragma unroll
    for (int j = 0; j < 4; ++j) acc[i][j] = zero;

  int nkt = K / BK;
  for (int kt = 0; kt < nkt; ++kt) {
#pragma unroll
    for (int it = 0; it < 4; ++it) {
      int s = it * 256 + tid;
      int row = s >> 3, cs = s & 7;
      gload16(A + (size_t)(m0 + row) * lda + kt * BK + cs * 8,
              lA + (size_t)(it * 256 + (tid & ~63)) * 8);
      gload16(B + (size_t)(n0 + row) * ldb + kt * BK + cs * 8,
              lB + (size_t)(it * 256 + (tid & ~63)) * 8);
    }
    __syncthreads();
#pragma unroll
    for (int ks = 0; ks < 2; ++ks) {
      bf16x8 af[4], bfr[4];
#pragma unroll
      for (int fm = 0; fm < 4; ++fm) {
        int rowa = wm * 64 + fm * 16 + (lane & 15);
        af[fm] = *(const bf16x8*)&lA[rowa * BK + ks * 32 + ((lane >> 4) << 3)];
      }
#pragma unroll
      for (int fn = 0; fn < 4; ++fn) {
        int rowb = wn * 64 + fn * 16 + (lane & 15);
        bfr[fn] = *(const bf16x8*)&lB[rowb * BK + ks * 32 + ((lane >> 4) << 3)];
      }
#pragma unroll
      for (int fm = 0; fm < 4; ++fm)
#pragma unroll
        for (int fn = 0; fn < 4; ++fn)
          acc[fm][fn] = __builtin_amdgcn_mfma_f32_16x16x32_bf16(af[fm], bfr[fn], acc[fm][fn], 0, 0, 0);
    }
    __syncthreads();
  }
#pragma unroll
  for (int fm = 0; fm < 4; ++fm) {
#pragma unroll
    for (int fn = 0; fn < 4; ++fn) {
      int col = n0 + wn * 64 + fn * 16 + (lane & 15);
      float b = bias[col];
#pragma unroll
      for (int v = 0; v < 4; ++v) {
        int row = m0 + wm * 64 + fm * 16 + ((lane >> 4) << 2) + v;
        float val = acc[fm][fn][v] + b;
        if (relu) val = fmaxf(val, 0.0f);
        C[(size_t)row * ldc + col] = f2bf(val);
      }
    }
  }
}

// ---------------- phase-B: persistent GRU recurrence (LDS-free, WHH in VGPRs) ----------------
// 256 WGs = 16 mt (64 n) x 16 jt (32 j). 4 waves: (wj = j-block of 16, wn = n-half of 32).
// WHH fragments (48 = 192 VGPR) loaded ONCE via plain compiler loads.
// Hin streamed per-nt with round-4-proven load_cc + WAITVM(8)/WAITVM(0).
// Sync: round-4-proven tid0-spin (relaxed, s_sleep) + __syncthreads + relaxed flag.
__global__ __launch_bounds__(256, 1) void gru_persistent(
    const u16* __restrict__ GI,    // (TN,1536) bf16, gi = x@W_ih^T + b_ih
    const u16* __restrict__ WHH,   // (1536,512) bf16
    u16* __restrict__ Hsave,       // (T_+1, N_, 512) bf16; slot 0 = h_init
    const float* __restrict__ hxs, // initial h f32 at [n*S_+2+j]
    const float* __restrict__ bhh, // (1536)
    int* __restrict__ bar)         // [16][T_] zeroed before launch
{
  int tid = threadIdx.x;
  int lane = tid & 63;
  int wave = tid >> 6;
  int wj = wave >> 1, wn = wave & 1;
  int bid = blockIdx.x;
  int mt = bid & 15, jt = bid >> 4;
  int n0 = mt * 64 + wn * 32;          // wave's n base (32 rows)
  int jb = jt * 32 + wj * 16;          // wave's j base (16 cols)
  int l15 = lane & 15, l4 = lane >> 4;
  int jt4 = l4 * 4;

  // ---- WHH fragments into VGPRs via PLAIN loads (compiler-managed waits)
  bf16x8 afr[3][16];
#pragma unroll
  for (int g = 0; g < 3; ++g) {
    const u16* base = WHH + (size_t)(g * 512 + jb + l15) * 512 + l4 * 8;
#pragma unroll
    for (int kk = 0; kk < 16; ++kk)
      afr[g][kk] = *(const bf16x8*)(base + kk * 32);
  }

  // ---- per-lane constants: biases (j = jb+jt4+v), initial h f32
  float bb[3][4];
#pragma unroll
  for (int g = 0; g < 3; ++g)
#pragma unroll
    for (int v = 0; v < 4; ++v) bb[g][v] = bhh[g * 512 + jb + jt4 + v];

  float hreg[2][4];
#pragma unroll
  for (int nt = 0; nt < 2; ++nt)
#pragma unroll
    for (int v = 0; v < 4; ++v)
      hreg[nt][v] = hxs[(size_t)(n0 + nt * 16 + l15) * S_ + 2 + jb + jt4 + v];

  for (int t = 0; t < T_; ++t) {
    const u16* Hin = Hsave + (size_t)t * (N_ * 512);
    u16* Hout = Hsave + (size_t)(t + 1) * (N_ * 512);
    const size_t tb = (size_t)t * N_;

    // ---- gi loads (plain, L2-cached), issued before the spin so latency hides
    uint2 giu[2][3];
#pragma unroll
    for (int nt = 0; nt < 2; ++nt) {
      const u16* gr = GI + (tb + n0 + nt * 16 + l15) * 1536 + jb + jt4;
#pragma unroll
      for (int g = 0; g < 3; ++g)
        giu[nt][g] = *(const uint2*)(gr + (size_t)g * 512);
    }

    if (t > 0) {
      if (tid == 0) {
        const int* cptr = bar + mt * T_ + (t - 1);
        while (__hip_atomic_load(cptr, __ATOMIC_RELAXED, __HIP_MEMORY_SCOPE_AGENT) < 16)
          __builtin_amdgcn_s_sleep(2);
      }
      __syncthreads();   // WG released once flag seen; no cache maintenance
    }

    f32x4 zero = {0.f, 0.f, 0.f, 0.f};
    f32x4 acc[2][3] = {{zero, zero, zero}, {zero, zero, zero}};

    // ---- per-nt: 16 LLC-coherent loads, split-wait, 48 MFMA from registers
#pragma unroll
    for (int nt = 0; nt < 2; ++nt) {
      bf16x8 areg[16];
      const u16* arow = Hin + (size_t)(n0 + nt * 16 + l15) * 512 + l4 * 8;
#pragma unroll
      for (int kk = 0; kk < 16; ++kk) areg[kk] = load_cc(arow + kk * 32);
      WAITVM(8);
#pragma unroll
      for (int kk = 0; kk < 8; ++kk)
#pragma unroll
        for (int g = 0; g < 3; ++g)
          acc[nt][g] = __builtin_amdgcn_mfma_f32_16x16x32_bf16(afr[g][kk], areg[kk], acc[nt][g], 0, 0, 0);
      WAITVM(0);
#pragma unroll
      for (int kk = 8; kk < 16; ++kk)
#pragma unroll
        for (int g = 0; g < 3; ++g)
          acc[nt][g] = __builtin_amdgcn_mfma_f32_16x16x32_bf16(afr[g][kk], areg[kk], acc[nt][g], 0, 0, 0);
    }

    // ---- epilogue: gates, h update, one 8B store per n-tile ----
#pragma unroll
    for (int nt = 0; nt < 2; ++nt) {
      int n = n0 + nt * 16 + l15;
      u32 pk0 = 0, pk1 = 0;
#pragma unroll
      for (int v = 0; v < 4; ++v) {
        float r = sigm(gi_get(giu[nt][0], v) + acc[nt][0][v] + bb[0][v]);
        float z = sigm(gi_get(giu[nt][1], v) + acc[nt][1][v] + bb[1][v]);
        float nn = tanhf(gi_get(giu[nt][2], v) + r * (acc[nt][2][v] + bb[2][v]));
        float h = (1.0f - z) * nn + z * hreg[nt][v];
        hreg[nt][v] = h;
        u32 hb = (u32)f2bf(h);
        if (v == 0) pk0 = hb;
        else if (v == 1) pk0 |= hb << 16;
        else if (v == 2) pk1 = hb;
        else pk1 |= hb << 16;
      }
      uint2 pk; pk.x = pk0; pk.y = pk1;
      store_cc_d2(Hout + (size_t)n * 512 + jb + jt4, pk);
    }

    if (t < T_ - 1) {
      WAITVM(0);         // own sc1 stores visible at LLC
      __syncthreads();   // all threads drained
      if (tid == 0)
        __hip_atomic_fetch_add(bar + mt * T_ + t, 1, __ATOMIC_RELAXED, __HIP_MEMORY_SCOPE_AGENT);
    }
  }
}

// ---------------- phase-C: heads + h expand + probs + p, batched over all (t,n) ----------------
__global__ __launch_bounds__(256) void heads_kernel(
    const u16* __restrict__ Hsave,
    const float* __restrict__ Wc, const float* __restrict__ bc,
    const float* __restrict__ Wa, const float* __restrict__ ba,
    const int* __restrict__ actions, const int* __restrict__ qpre,
    const int* __restrict__ qpost, float* __restrict__ out)
{
  int row = blockIdx.x * 4 + (threadIdx.x >> 6);
  int lane = threadIdx.x & 63;
  // Hsave slot (t+1) for row = t*N+n  ->  (N_ + row)
  const u16x8 hv8 = *(const u16x8*)(Hsave + (size_t)(N_ + row) * 512 + lane * 8);
  float* oh = out + (size_t)row * S_ + 2 + lane * 8;
  float pc = 0, p0 = 0, p1 = 0, p2 = 0, p3 = 0;
#pragma unroll
  for (int jj = 0; jj < 8; ++jj) {
    int k = lane * 8 + jj;
    float hv = bf2f(hv8[jj]);
    oh[jj] = hv;
    pc += hv * Wc[k];
    p0 += hv * Wa[k];
    p1 += hv * Wa[512 + k];
    p2 += hv * Wa[1024 + k];
    p3 += hv * Wa[1536 + k];
  }
#pragma unroll
  for (int m = 1; m < 64; m <<= 1) {
    pc += __shfl_xor(pc, m);
    p0 += __shfl_xor(p0, m);
    p1 += __shfl_xor(p1, m);
    p2 += __shfl_xor(p2, m);
    p3 += __shfl_xor(p3, m);
  }
  float v = pc + bc[0];
  float k0 = p0 + ba[0], k1 = p1 + ba[1], k2 = p2 + ba[2], k3 = p3 + ba[3];
  float mx = fmaxf(k0, fmaxf(k1, k2));
  float e0 = __expf(k0 - mx), e1 = __expf(k1 - mx), e2 = __expf(k2 - mx);
  float es = e0 + e1 + e2;
  float l0 = e0 / es, l1 = e1 / es, l2 = e2 / es;
  float no = sigm(k3);
  float total = (1.0f - no) * (l0 + l1 + l2) + no;
  float sc = (1.0f - no) / total;
  int q = qpre[row], qp = qpost[row];
  int a = actions[row];
  if (lane == 0) {
    out[(size_t)row * S_] = (float)a;
    out[(size_t)row * S_ + 1] = v;
  }
  float* pr = out + (size_t)row * S_ + 2 + H_;
  for (int c = lane; c < L_ + 1; c += 64) {
    float val;
    if (c == L_) val = no / total;
    else {
      val = 0.f;
      if (q == 0)            { if (c == 0) val = l1 + l2; else if (c == 1) val = l0; }
      else if (q == L_ - 1)  { if (c == L_ - 2) val = l2; else if (c == L_ - 1) val = l0 + l1; }
      else                   { if (c == q - 1) val = l2; else if (c == q) val = l1; else if (c == q + 1) val = l0; }
      val *= sc;
    }
    pr[c] = val;
  }
  float* pp = pr + (L_ + 1);
  for (int c = lane; c < L_; c += 64) pp[c] = (c == qp) ? 1.0f : 0.0f;
}

__global__ void copy_last(float* __restrict__ out) {
  int i = blockIdx.x * 256 + threadIdx.x;
  if (i < N_ * S_) out[(size_t)TN_ * S_ + i] = out[(size_t)(T_ - 1) * N_ * S_ + i];
}

// ---------------- launch ----------------
extern "C" void kernel_launch(void* const* d_in, const int* in_sizes, int n_in,
                              void* d_out, int out_size, void* d_ws, size_t ws_size,
                              hipStream_t stream) {
  const float* cond = (const float*)d_in[0];
  const float* hxs  = (const float*)d_in[1];
  const float* emb  = (const float*)d_in[2];
  const float* W0   = (const float*)d_in[3];
  const float* b0   = (const float*)d_in[4];
  const float* W1   = (const float*)d_in[5];
  const float* b1   = (const float*)d_in[6];
  const float* W2   = (const float*)d_in[7];
  const float* b2   = (const float*)d_in[8];
  const float* Wih  = (const float*)d_in[9];
  const float* bih  = (const float*)d_in[10];
  const float* Whh  = (const float*)d_in[11];
  const float* bhh  = (const float*)d_in[12];
  const float* Wc   = (const float*)d_in[13];
  const float* bc   = (const float*)d_in[14];
  const float* Wa   = (const float*)d_in[15];
  const float* ba   = (const float*)d_in[16];
  const int* lines   = (const int*)d_in[17];
  const int* actions = (const int*)d_in[18];
  float* out = (float*)d_out;

  char* ws = (char*)d_ws;
  size_t off = 0;
  auto alloc = [&](size_t bytes) {
    char* p = ws + off;
    off += (bytes + 255) & ~(size_t)255;
    return p;
  };
  u16* P = (u16*)alloc((size_t)TN_ * 576 * 2);    // Abuf, then X2
  u16* Q = (u16*)alloc((size_t)TN_ * 512 * 2);    // X1, then X3
  u16* GIb = (u16*)alloc((size_t)TN_ * 1536 * 2); // gi (201MB)
  u16* Abuf = P;
  u16* X1 = Q;
  u16* X2 = P;
  u16* X3 = Q;
  u16* W0b = (u16*)alloc((size_t)512 * 576 * 2);
  u16* W1b = (u16*)alloc((size_t)512 * 512 * 2);
  u16* W2b = (u16*)alloc((size_t)512 * 512 * 2);
  u16* WIHb = (u16*)alloc((size_t)1536 * 512 * 2);
  u16* WHHb = (u16*)alloc((size_t)1536 * 512 * 2);
  int* qpre  = (int*)alloc((size_t)TN_ * 4);
  int* qpost = (int*)alloc((size_t)TN_ * 4);
  u16* Hsave = (u16*)alloc((size_t)(T_ + 1) * N_ * 512 * 2);  // 68MB
  int* bar = (int*)alloc((size_t)16 * T_ * 4);

  hipMemsetAsync(bar, 0, (size_t)16 * T_ * 4, stream);

  cast_f32_bf16<<<(512 * 576 + 255) / 256, 256, 0, stream>>>(W0, W0b, 512 * 576);
  cast_f32_bf16<<<(512 * 512 + 255) / 256, 256, 0, stream>>>(W1, W1b, 512 * 512);
  cast_f32_bf16<<<(512 * 512 + 255) / 256, 256, 0, stream>>>(W2, W2b, 512 * 512);
  cast_f32_bf16<<<(1536 * 512 + 255) / 256, 256, 0, stream>>>(Wih, WIHb, 1536 * 512);
  cast_f32_bf16<<<(1536 * 512 + 255) / 256, 256, 0, stream>>>(Whh, WHHb, 1536 * 512);
  qscan<<<4, 256, 0, stream>>>(hxs, actions, qpre, qpost);
  hbf_init<<<(N_ * 512 + 255) / 256, 256, 0, stream>>>(hxs, Hsave);
  build_abuf<<<TN_ / 4, 256, 0, stream>>>(cond, emb, lines, qpre, Abuf);

  gemm_nt<<<dim3(4, 512), 256, 0, stream>>>(Abuf, 576, W0b, 576, b0, X1, 512, 576, 1);
  gemm_nt<<<dim3(4, 512), 256, 0, stream>>>(X1, 512, W1b, 512, b1, X2, 512, 512, 1);
  gemm_nt<<<dim3(4, 512), 256, 0, stream>>>(X2, 512, W2b, 512, b2, X3, 512, 512, 1);
  gemm_nt<<<dim3(12, 512), 256, 0, stream>>>(X3, 512, WIHb, 512, bih, GIb, 1536, 512, 0);

  gru_persistent<<<256, 256, 0, stream>>>(GIb, WHHb, Hsave, hxs, bhh, bar);

  heads_kernel<<<TN_ / 4, 256, 0, stream>>>(Hsave, Wc, bc, Wa, ba, actions, qpre, qpost, out);
  copy_last<<<(N_ * S_ + 255) / 256, 256, 0, stream>>>(out);
}